// Round 4
// baseline (809.597 us; speedup 1.0000x reference)
//
#include <hip/hip_runtime.h>

typedef unsigned short u16;
typedef __attribute__((ext_vector_type(8))) _Float16 f16x8;
typedef __attribute__((ext_vector_type(4))) float f32x4;
typedef __attribute__((ext_vector_type(4))) int i32x4;
typedef __attribute__((ext_vector_type(4))) unsigned short us4;

__device__ __forceinline__ u16 f2h(float f) {
  _Float16 h = (_Float16)f;
  return __builtin_bit_cast(unsigned short, h);
}
__device__ __forceinline__ float sigm(float v) { return 1.0f / (1.0f + __expf(-v)); }
__device__ __forceinline__ float tanh_(float v) {
  float t = __expf(-2.0f * fabsf(v));
  float r = (1.0f - t) / (1.0f + t);
  return v >= 0.0f ? r : -r;
}

// async global->LDS DMA, 16 B per lane; LDS dest = wave-uniform base + lane*16
typedef const __attribute__((address_space(1))) unsigned int* gas_t;
typedef __attribute__((address_space(3))) unsigned int* las_t;
__device__ __forceinline__ void gl16(const u16* g, u16* l) {
  __builtin_amdgcn_global_load_lds((gas_t)g, (las_t)l, 16, 0, 0);
}

// ---------------------------------------------------------------------------
// prep_scores: [es 8][p 256] blocks. DMA-staged this round: 64 KB WQ slice
// global_load_lds'd into LDS (16x1KB per wave, deep queue, zero VGPR
// pressure -- the register version kept serializing at VGPR=44), then
// m[t] = sum_e wk[e]*L[e][t] from LDS, then 8-batch shuffle reduce.
// Block 0 also computes sb.
// ---------------------------------------------------------------------------
__global__ __launch_bounds__(256) void prep_scores(
    const float* __restrict__ WQ, const float* __restrict__ WK,
    const float* __restrict__ txt, const float* __restrict__ WV,
    const float* __restrict__ Wsw, const float* __restrict__ Wsb,
    float* __restrict__ scores, float* __restrict__ sb) {
  __shared__ __align__(16) float L[64 * 256];   // 64 KB staged WQ rows
  __shared__ float wk[64];
  __shared__ float red[4][8];
  __shared__ float red2[4];
  int tid = threadIdx.x;
  int lane = tid & 63, wave = tid >> 6;
  int p = blockIdx.x & 255;
  int es = blockIdx.x >> 8;                    // e-slice 0..7
  // stage 64 e-rows (1 KB each): wave w covers rows w*16..w*16+15
  const float* src = WQ + ((size_t)p * 512 + es * 64 + wave * 16) * 256;
  u16* ldst = (u16*)&L[wave * 16 * 256];
#pragma unroll
  for (int r = 0; r < 16; ++r)
    gl16((const u16*)(src + (size_t)r * 256 + lane * 4), ldst + r * 512);
  if (tid < 64) wk[tid] = WK[es * 64 + tid];
  __syncthreads();                             // drains DMA (vmcnt0) + wk
  float a0 = 0.f, a1 = 0.f, a2 = 0.f, a3 = 0.f;
#pragma unroll
  for (int e = 0; e < 64; e += 4) {
    a0 = fmaf(L[(e + 0) * 256 + tid], wk[e + 0], a0);
    a1 = fmaf(L[(e + 1) * 256 + tid], wk[e + 1], a1);
    a2 = fmaf(L[(e + 2) * 256 + tid], wk[e + 2], a2);
    a3 = fmaf(L[(e + 3) * 256 + tid], wk[e + 3], a3);
  }
  float m = (a0 + a1) + (a2 + a3);
  float v[8];
#pragma unroll
  for (int b = 0; b < 8; ++b) v[b] = m * txt[b * 256 + tid];
#pragma unroll
  for (int off = 32; off; off >>= 1)
#pragma unroll
    for (int b = 0; b < 8; ++b) v[b] += __shfl_down(v[b], off, 64);
  if (lane == 0)
#pragma unroll
    for (int b = 0; b < 8; ++b) red[wave][b] = v[b];
  __syncthreads();
  if (tid < 8) {
    float sv = red[0][tid] + red[1][tid] + red[2][tid] + red[3][tid];
    atomicAdd(&scores[tid * 256 + p], sv * 0.044194173824159216f);
  }
  if (blockIdx.x == 0) {
    float vv = WV[tid] * Wsw[tid] + WV[tid + 256] * Wsw[tid + 256];
#pragma unroll
    for (int off = 32; off; off >>= 1) vv += __shfl_down(vv, off, 64);
    if (lane == 0) red2[wave] = vv;
    __syncthreads();
    if (tid == 0) {
      sb[0] = red2[0] + red2[1] + red2[2] + red2[3];
      sb[1] = Wsb[0];
    }
  }
}

// ---------------------------------------------------------------------------
// prep_swz: [set 2][chgrp 32][chunk 16] blocks x 512 threads. Each thread:
// 9 f32x4 loads (36 contiguous floats = 4 channel-rows x 9 taps -- small
// enough that the compiler keeps them batched), 9x 8B stores into the
// FRAGMENT-MAJOR layout: u16 idx = ((k9*4+gate)*64 + q*16+chrow)*8 + c8,
// so conv4's A ds_read_b128 is linear lane*16 (0 conflicts).
// ---------------------------------------------------------------------------
__global__ __launch_bounds__(512) void prep_swz(
    const float* __restrict__ wi, const float* __restrict__ wf,
    const float* __restrict__ wo, const float* __restrict__ wc,
    const float* __restrict__ ui, const float* __restrict__ uf,
    const float* __restrict__ uo, const float* __restrict__ uc,
    u16* __restrict__ dstW, u16* __restrict__ dstU) {
  int tid = threadIdx.x;
  int set = blockIdx.x >> 9;
  int chgrp = (blockIdx.x >> 4) & 31;
  int chunk = blockIdx.x & 15;
  int gate = tid >> 7, chrow = (tid >> 3) & 15, oct = tid & 7;
  int q = oct >> 1, c0 = (oct & 1) * 4;        // channels cl = q*8 + c0 .. +3
  int ch = chgrp * 16 + chrow;
  const float* s;
  if (set == 0) s = gate == 0 ? wi : gate == 1 ? wf : gate == 2 ? wo : wc;
  else          s = gate == 0 ? ui : gate == 1 ? uf : gate == 2 ? uo : uc;
  const f32x4* src = (const f32x4*)(s + ((size_t)(ch * 512 + chunk * 32) + q * 8 + c0) * 9);
  f32x4 va[9];                                 // f[cl'*9 + k9], cl' = 0..3
#pragma unroll
  for (int i = 0; i < 9; ++i) va[i] = src[i];
  u16* dst = (set == 0 ? dstW : dstU) + (size_t)(chgrp * 16 + chunk) * 18432
             + (size_t)(gate * 64 + q * 16 + chrow) * 8 + c0;
#pragma unroll
  for (int k9 = 0; k9 < 9; ++k9) {
    us4 wv;
#pragma unroll
    for (int c = 0; c < 4; ++c) {
      int i = c * 9 + k9;
      wv[c] = f2h(va[i >> 2][i & 3]);
    }
    *(us4*)(dst + (size_t)k9 * 2048) = wv;
  }
}

// ---------------------------------------------------------------------------
// prep_inputs: coef from scores (softmax over h per (b,w)); AM = coef*x,
// H0 = x, fp16 PADDED NHWC [b][18 r][18 c][512 ch] (borders pre-zeroed by
// memset; only interior written here) so conv4 B-loads need no masking.
// ---------------------------------------------------------------------------
__global__ void prep_inputs(const float* __restrict__ x, const float* __restrict__ scores,
                            const float* __restrict__ sb,
                            u16* __restrict__ AM, u16* __restrict__ H0) {
  __shared__ float sc[16];
  int idx = blockIdx.x * 256 + threadIdx.x;
  int ch = idx & 511, p = (idx >> 9) & 255, b = idx >> 17;
  int w = p & 15, h = p >> 4;
  if (threadIdx.x < 16) sc[threadIdx.x] = scores[b * 256 + threadIdx.x * 16 + w];
  __syncthreads();
  float s = sb[0], b0 = sb[1];
  float mx = -1e30f;
#pragma unroll
  for (int hh = 0; hh < 16; ++hh) mx = fmaxf(mx, sc[hh]);
  float den = 0.f, my = 0.f;
#pragma unroll
  for (int hh = 0; hh < 16; ++hh) {
    float e = __expf(sc[hh] - mx);
    den += e;
    if (hh == h) my = e;
  }
  float coef = 1.0f + b0 + s * my / den;
  float xv = x[(size_t)(b * 512 + ch) * 256 + p];
  size_t o = (size_t)b * 165888 + (size_t)((h + 1) * 18 + (w + 1)) * 512 + ch;
  AM[o] = f2h(coef * xv);
  H0[o] = f2h(xv);
}

// ---------------------------------------------------------------------------
// Fused 4-gate 3x3 conv, implicit GEMM (fp16 MFMA 16x16x32, fp32 acc).
// RESTRUCTURED this round for the latency-bound diagnosis (occ 20%, all
// pipes <40%, 4.7M LDS conflicts):
//  - B (input) NO LONGER IN LDS: 12 global_load_dwordx4/wave/chunk straight
//    from padded [18][18][512] images (L1/L2-resident). Kills ALL measured
//    bank conflicts (A reads are linear lane*16) and the B-DMA barrier dep.
//  - LDS = A double-buffer only (2x36864 = 73.7 KB) -> 2 blocks/CU.
//  - Grid 512 = [b 8][nhalf 2][chgrp 32], 512 thr, N=128/block -> 2 resident
//    blocks/CU = 16 waves/CU; one block computes while the other drains.
// Wave (mw=wave>>2, nw=wave&3) owns gates {2mw,2mw+1} x output rows
// {nhalf*8+nw*2, +1} -> acc[2][2], 36 MFMA/chunk/wave.
// MODE 0: chunks 0-15 = W on AM (G=acc+biases at k==15), 16-31 = U on H0;
//         LSTM c_src=x.  MODE 1: z=acc+G; LSTM; c,h out.  MODE 2: d_out.
// ---------------------------------------------------------------------------
template <int MODE>
__launch_bounds__(512, 4)
__global__ void conv4(const u16* __restrict__ inA, const u16* __restrict__ inH,
                      const u16* __restrict__ wW, const u16* __restrict__ wU,
                      const float* __restrict__ bWi, const float* __restrict__ bUi,
                      const float* __restrict__ bWf, const float* __restrict__ bUf,
                      const float* __restrict__ bWo, const float* __restrict__ bUo,
                      const float* __restrict__ bWc, const float* __restrict__ bUc,
                      float* __restrict__ G, const float* __restrict__ c_src,
                      float* __restrict__ c_dst, u16* __restrict__ h_out,
                      float* __restrict__ out) {
  __shared__ __align__(16) u16 Alds[2][9 * 4 * 64 * 8];  // [k9][gate][lane][8]
  const int tid = threadIdx.x;
  const int chgrp = blockIdx.x & 31;
  const int nhalf = (blockIdx.x >> 5) & 1;
  const int b = blockIdx.x >> 6;
  const int wave = tid >> 6, lane = tid & 63;
  const int row = lane & 15, quad = lane >> 4;
  const int nw = wave & 3, mw = wave >> 2;
  const int NCH = (MODE == 0) ? 32 : 16;
  const int r0 = nhalf * 8 + nw * 2;            // wave's first output row

  const u16* wsrcW = wW + (size_t)chgrp * 294912;
  const u16* wsrcU = wU + (size_t)chgrp * 294912;
  const u16* imgA = inA + (size_t)b * 165888;   // padded [18][18][512]
  const u16* imgH = inH + (size_t)b * 165888;

  auto stageA = [&](int k, int bb) {
    const u16* gw = (MODE == 0 && k < 16) ? wsrcW + k * 18432 : wsrcU + (k & 15) * 18432;
    u16* Ab = &Alds[bb][0];
#pragma unroll
    for (int i = 0; i < 5; ++i) {
      int idx = i * 8 + wave;
      if (idx < 36) gl16(gw + (idx * 64 + lane) * 8, &Ab[idx * 512]);
    }
  };

  f32x4 acc[2][2];
#pragma unroll
  for (int m = 0; m < 2; ++m)
#pragma unroll
    for (int n = 0; n < 2; ++n) acc[m][n] = (f32x4){0.f, 0.f, 0.f, 0.f};

  const int ch0 = chgrp * 16 + quad * 4;
  float* gptr = G + (size_t)blockIdx.x * 8192 + wave * 1024 + lane * 4;

  stageA(0, 0);
  __syncthreads();                              // chunk-0 weights ready
  int bb = 0;

#pragma unroll 1
  for (int k = 0; k < NCH; ++k) {
    if (k + 1 < NCH) stageA(k + 1, bb ^ 1);     // next-chunk A-DMA first
    // B fragments: direct global loads (padded image, no masking)
    const u16* img = (MODE == 0 && k < 16) ? imgA : imgH;
    const u16* ibase = img + (size_t)(k & 15) * 32 + quad * 8;
    f16x8 bfr[3][4];                            // [kx][input row jj]
#pragma unroll
    for (int kx = 0; kx < 3; ++kx)
#pragma unroll
      for (int jj = 0; jj < 4; ++jj)
        bfr[kx][jj] = *(const f16x8*)(ibase + (size_t)((r0 + jj) * 18 + row + kx) * 512);
    const u16* Ab = &Alds[bb][0];
#pragma unroll
    for (int kx = 0; kx < 3; ++kx) {
      f16x8 afr[6];                             // (ky 0..2) x (m 0..1)
#pragma unroll
      for (int ky = 0; ky < 3; ++ky)
#pragma unroll
        for (int m = 0; m < 2; ++m)
          afr[ky * 2 + m] = *(const f16x8*)(&Alds[bb][((ky * 3 + kx) * 4 + 2 * mw + m) * 512 + lane * 8]);
#pragma unroll
      for (int ky = 0; ky < 3; ++ky)
#pragma unroll
        for (int m = 0; m < 2; ++m)
#pragma unroll
          for (int n = 0; n < 2; ++n)
            acc[m][n] = __builtin_amdgcn_mfma_f32_16x16x32_f16(afr[ky * 2 + m], bfr[kx][n + ky],
                                                               acc[m][n], 0, 0, 0);
    }
    (void)Ab;
    if constexpr (MODE == 0) {
      if (k == 15) {  // W-half done: add biases, persist G = conv(AM,W)+bW+bU
#pragma unroll
        for (int m = 0; m < 2; ++m) {
          int g = 2 * mw + m;
          const float* bw = g == 0 ? bWi : g == 1 ? bWf : g == 2 ? bWo : bWc;
          const float* bu = g == 0 ? bUi : g == 1 ? bUf : g == 2 ? bUo : bUc;
          f32x4 bias;
#pragma unroll
          for (int r = 0; r < 4; ++r) bias[r] = bw[ch0 + r] + bu[ch0 + r];
#pragma unroll
          for (int n = 0; n < 2; ++n) {
            acc[m][n] = acc[m][n] + bias;
            *(f32x4*)(gptr + (m * 2 + n) * 256) = acc[m][n];
          }
        }
      }
    }
    __syncthreads();  // waves done reading Alds[bb]; DMA into bb^1 drained
    bb ^= 1;
  }

  // ---- epilogue: reunite gates (mw=1 -> mw=0 via LDS), LSTM update ----
  if constexpr (MODE != 0) {
#pragma unroll
    for (int m = 0; m < 2; ++m)
#pragma unroll
      for (int n = 0; n < 2; ++n)
        acc[m][n] = acc[m][n] + *(const f32x4*)(gptr + (m * 2 + n) * 256);
  }
  float* X = (float*)&Alds[0][0];  // 16 KB exchange buffer (Alds[0] is dead)
  if (mw == 1) {
#pragma unroll
    for (int m = 0; m < 2; ++m)
#pragma unroll
      for (int n = 0; n < 2; ++n)
        *(f32x4*)(X + (size_t)((nw * 4 + m * 2 + n) * 256) + lane * 4) = acc[m][n];
  }
  __syncthreads();
  if (mw == 0) {
#pragma unroll
    for (int n = 0; n < 2; ++n) {
      const int p = (r0 + n) * 16 + row;
      f32x4 zi = acc[0][n], zf = acc[1][n];
      f32x4 zo = *(const f32x4*)(X + (size_t)((nw * 4 + n) * 256) + lane * 4);
      f32x4 zg = *(const f32x4*)(X + (size_t)((nw * 4 + 2 + n) * 256) + lane * 4);
      f32x4 cold;
#pragma unroll
      for (int r = 0; r < 4; ++r)
        cold[r] = c_src[(size_t)(b * 512 + ch0 + r) * 256 + p];
      f32x4 cnew, hv;
#pragma unroll
      for (int r = 0; r < 4; ++r) {
        float iv = sigm(zi[r]);
        float fv = sigm(zf[r]);
        float ov = sigm(zo[r]);
        float gv = tanh_(zg[r]);
        float cn = fmaf(gv, iv, fv * cold[r]);
        cnew[r] = cn;
        hv[r] = tanh_(cn) * ov;
      }
      if constexpr (MODE != 2) {
#pragma unroll
        for (int r = 0; r < 4; ++r)
          c_dst[(size_t)(b * 512 + ch0 + r) * 256 + p] = cnew[r];
        us4 hb;
        hb[0] = f2h(hv[0]); hb[1] = f2h(hv[1]);
        hb[2] = f2h(hv[2]); hb[3] = f2h(hv[3]);
        *(us4*)(h_out + (size_t)b * 165888 + (size_t)((r0 + n + 1) * 18 + row + 1) * 512 + ch0) = hb;
      } else {
#pragma unroll
        for (int r = 0; r < 4; ++r)
          out[(size_t)(b * 512 + ch0 + r) * 256 + p] = hv[r];
      }
    }
  }
}

extern "C" void kernel_launch(void* const* d_in, const int* in_sizes, int n_in,
                              void* d_out, int out_size, void* d_ws, size_t ws_size,
                              hipStream_t stream) {
  const float* x    = (const float*)d_in[0];
  const float* txt  = (const float*)d_in[1];
  const float* Wi_w = (const float*)d_in[7];
  const float* Wi_b = (const float*)d_in[8];
  const float* Ui_w = (const float*)d_in[9];
  const float* Ui_b = (const float*)d_in[10];
  const float* Wf_w = (const float*)d_in[11];
  const float* Wf_b = (const float*)d_in[12];
  const float* Uf_w = (const float*)d_in[13];
  const float* Uf_b = (const float*)d_in[14];
  const float* Wc_w = (const float*)d_in[15];
  const float* Wc_b = (const float*)d_in[16];
  const float* Uc_w = (const float*)d_in[17];
  const float* Uc_b = (const float*)d_in[18];
  const float* Wo_w = (const float*)d_in[19];
  const float* Wo_b = (const float*)d_in[20];
  const float* Uo_w = (const float*)d_in[21];
  const float* Uo_b = (const float*)d_in[22];
  const float* WQ   = (const float*)d_in[23];
  const float* WK   = (const float*)d_in[24];
  const float* WV   = (const float*)d_in[25];
  const float* Wsw  = (const float*)d_in[26];
  const float* Wsb  = (const float*)d_in[27];
  (void)in_sizes; (void)n_in; (void)ws_size;

  char* ws = (char*)d_ws;
  size_t off = 0;
  auto carve = [&](size_t n) {
    char* p = ws + off;
    off += (n + 255) & ~(size_t)255;
    return p;
  };
  u16* WswzW    = (u16*)carve(18874368);   // 4x512x512x9 fp16, fragment-major
  u16* WswzU    = (u16*)carve(18874368);
  u16* AM       = (u16*)carve(2654208);    // fp16 padded [8][18][18][512]
  u16* H0       = (u16*)carve(2654208);
  u16* H1       = (u16*)carve(2654208);
  float* G      = (float*)carve(16777216); // fragment-layout W-conv + biases
  float* C      = (float*)carve(4194304);  // cell state, NCHW f32
  float* scores = (float*)carve(8192);     // [8 b][256 p]
  float* sb     = (float*)carve(256);      // s, b0

  hipMemsetAsync(scores, 0, 8192, stream);   // scores accumulated via atomicAdd
  hipMemsetAsync(AM, 0, 2654208, stream);    // zero borders of padded images
  hipMemsetAsync(H0, 0, 2654208, stream);
  hipMemsetAsync(H1, 0, 2654208, stream);

  prep_scores<<<2048, 256, 0, stream>>>(WQ, WK, txt, WV, Wsw, Wsb, scores, sb);
  prep_swz<<<1024, 512, 0, stream>>>(Wi_w, Wf_w, Wo_w, Wc_w,
                                     Ui_w, Uf_w, Uo_w, Uc_w, WswzW, WswzU);
  prep_inputs<<<4096, 256, 0, stream>>>(x, scores, sb, AM, H0);

  // t=0 fused (W on AM + U on H0), then 3 more timesteps ping-ponging h.
  conv4<0><<<512, 512, 0, stream>>>(AM, H0, WswzW, WswzU,
                                    Wi_b, Ui_b, Wf_b, Uf_b, Wo_b, Uo_b, Wc_b, Uc_b,
                                    G, x, C, H1, nullptr);
  conv4<1><<<512, 512, 0, stream>>>(nullptr, H1, nullptr, WswzU,
                                    nullptr, nullptr, nullptr, nullptr,
                                    nullptr, nullptr, nullptr, nullptr,
                                    G, C, C, H0, nullptr);
  conv4<1><<<512, 512, 0, stream>>>(nullptr, H0, nullptr, WswzU,
                                    nullptr, nullptr, nullptr, nullptr,
                                    nullptr, nullptr, nullptr, nullptr,
                                    G, C, C, H1, nullptr);
  conv4<2><<<512, 512, 0, stream>>>(nullptr, H1, nullptr, WswzU,
                                    nullptr, nullptr, nullptr, nullptr,
                                    nullptr, nullptr, nullptr, nullptr,
                                    G, C, nullptr, nullptr, (float*)d_out);
}

// Round 5
// 537.096 us; speedup vs baseline: 1.5074x; 1.5074x over previous
//
#include <hip/hip_runtime.h>

typedef unsigned short u16;
typedef __attribute__((ext_vector_type(8))) _Float16 f16x8;
typedef __attribute__((ext_vector_type(4))) float f32x4;
typedef __attribute__((ext_vector_type(4))) int i32x4;
typedef __attribute__((ext_vector_type(4))) unsigned short us4;

__device__ __forceinline__ u16 f2h(float f) {
  _Float16 h = (_Float16)f;
  return __builtin_bit_cast(unsigned short, h);
}
__device__ __forceinline__ float sigm(float v) { return 1.0f / (1.0f + __expf(-v)); }
__device__ __forceinline__ float tanh_(float v) {
  float t = __expf(-2.0f * fabsf(v));
  float r = (1.0f - t) / (1.0f + t);
  return v >= 0.0f ? r : -r;
}

// async global->LDS DMA, 16 B per lane; LDS dest = wave-uniform base + lane*16,
// global source is PER-LANE (used below to realize swizzled LDS layouts).
typedef const __attribute__((address_space(1))) unsigned int* gas_t;
typedef __attribute__((address_space(3))) unsigned int* las_t;
__device__ __forceinline__ void gl16(const u16* g, u16* l) {
  __builtin_amdgcn_global_load_lds((gas_t)g, (las_t)l, 16, 0, 0);
}

// ---------------------------------------------------------------------------
// prep_scores: [es 8][p 256] blocks. 64 KB WQ slice DMA-staged to LDS (16x1KB
// per wave, deep queue, no VGPR pressure), then m[t] = sum_e wk[e]*L[e][t],
// then 8-batch shuffle reduce. Block 0 also computes sb.
// ---------------------------------------------------------------------------
__global__ __launch_bounds__(256) void prep_scores(
    const float* __restrict__ WQ, const float* __restrict__ WK,
    const float* __restrict__ txt, const float* __restrict__ WV,
    const float* __restrict__ Wsw, const float* __restrict__ Wsb,
    float* __restrict__ scores, float* __restrict__ sb) {
  __shared__ __align__(16) float L[64 * 256];   // 64 KB staged WQ rows
  __shared__ float wk[64];
  __shared__ float red[4][8];
  __shared__ float red2[4];
  int tid = threadIdx.x;
  int lane = tid & 63, wave = tid >> 6;
  int p = blockIdx.x & 255;
  int es = blockIdx.x >> 8;                    // e-slice 0..7
  const float* src = WQ + ((size_t)p * 512 + es * 64 + wave * 16) * 256;
  u16* ldst = (u16*)&L[wave * 16 * 256];
#pragma unroll
  for (int r = 0; r < 16; ++r)
    gl16((const u16*)(src + (size_t)r * 256 + lane * 4), ldst + r * 512);
  if (tid < 64) wk[tid] = WK[es * 64 + tid];
  __syncthreads();                             // drains DMA (vmcnt0) + wk
  float a0 = 0.f, a1 = 0.f, a2 = 0.f, a3 = 0.f;
#pragma unroll
  for (int e = 0; e < 64; e += 4) {
    a0 = fmaf(L[(e + 0) * 256 + tid], wk[e + 0], a0);
    a1 = fmaf(L[(e + 1) * 256 + tid], wk[e + 1], a1);
    a2 = fmaf(L[(e + 2) * 256 + tid], wk[e + 2], a2);
    a3 = fmaf(L[(e + 3) * 256 + tid], wk[e + 3], a3);
  }
  float m = (a0 + a1) + (a2 + a3);
  float v[8];
#pragma unroll
  for (int b = 0; b < 8; ++b) v[b] = m * txt[b * 256 + tid];
#pragma unroll
  for (int off = 32; off; off >>= 1)
#pragma unroll
    for (int b = 0; b < 8; ++b) v[b] += __shfl_down(v[b], off, 64);
  if (lane == 0)
#pragma unroll
    for (int b = 0; b < 8; ++b) red[wave][b] = v[b];
  __syncthreads();
  if (tid < 8) {
    float sv = red[0][tid] + red[1][tid] + red[2][tid] + red[3][tid];
    atomicAdd(&scores[tid * 256 + p], sv * 0.044194173824159216f);
  }
  if (blockIdx.x == 0) {
    float vv = WV[tid] * Wsw[tid] + WV[tid + 256] * Wsw[tid + 256];
#pragma unroll
    for (int off = 32; off; off >>= 1) vv += __shfl_down(vv, off, 64);
    if (lane == 0) red2[wave] = vv;
    __syncthreads();
    if (tid == 0) {
      sb[0] = red2[0] + red2[1] + red2[2] + red2[3];
      sb[1] = Wsb[0];
    }
  }
}

// ---------------------------------------------------------------------------
// prep_swz: [set 2][chgrp 32][chunk 16] blocks x 512 threads. 9 f32x4 loads +
// 9x 8B stores into FRAGMENT-MAJOR layout:
//   u16 idx = ((k9*4+gate)*64 + q*16+chrow)*8 + c8
// so conv4's A ds_read_b128 is linear lane*16 (0 conflicts, R4-verified).
// ---------------------------------------------------------------------------
__global__ __launch_bounds__(512) void prep_swz(
    const float* __restrict__ wi, const float* __restrict__ wf,
    const float* __restrict__ wo, const float* __restrict__ wc,
    const float* __restrict__ ui, const float* __restrict__ uf,
    const float* __restrict__ uo, const float* __restrict__ uc,
    u16* __restrict__ dstW, u16* __restrict__ dstU) {
  int tid = threadIdx.x;
  int set = blockIdx.x >> 9;
  int chgrp = (blockIdx.x >> 4) & 31;
  int chunk = blockIdx.x & 15;
  int gate = tid >> 7, chrow = (tid >> 3) & 15, oct = tid & 7;
  int q = oct >> 1, c0 = (oct & 1) * 4;        // channels cl = q*8 + c0 .. +3
  int ch = chgrp * 16 + chrow;
  const float* s;
  if (set == 0) s = gate == 0 ? wi : gate == 1 ? wf : gate == 2 ? wo : wc;
  else          s = gate == 0 ? ui : gate == 1 ? uf : gate == 2 ? uo : uc;
  const f32x4* src = (const f32x4*)(s + ((size_t)(ch * 512 + chunk * 32) + q * 8 + c0) * 9);
  f32x4 va[9];                                 // f[cl'*9 + k9], cl' = 0..3
#pragma unroll
  for (int i = 0; i < 9; ++i) va[i] = src[i];
  u16* dst = (set == 0 ? dstW : dstU) + (size_t)(chgrp * 16 + chunk) * 18432
             + (size_t)(gate * 64 + q * 16 + chrow) * 8 + c0;
#pragma unroll
  for (int k9 = 0; k9 < 9; ++k9) {
    us4 wv;
#pragma unroll
    for (int c = 0; c < 4; ++c) {
      int i = c * 9 + k9;
      wv[c] = f2h(va[i >> 2][i & 3]);
    }
    *(us4*)(dst + (size_t)k9 * 2048) = wv;
  }
}

// ---------------------------------------------------------------------------
// prep_inputs: coef from scores (softmax over h per (b,w)); AM = coef*x,
// H0 = x, fp16 PADDED NHWC [b][18][18][512] (borders pre-zeroed by memset) so
// conv4's B staging DMA reads pads directly -- no masking, no LDS zeroing.
// ---------------------------------------------------------------------------
__global__ void prep_inputs(const float* __restrict__ x, const float* __restrict__ scores,
                            const float* __restrict__ sb,
                            u16* __restrict__ AM, u16* __restrict__ H0) {
  __shared__ float sc[16];
  int idx = blockIdx.x * 256 + threadIdx.x;
  int ch = idx & 511, p = (idx >> 9) & 255, b = idx >> 17;
  int w = p & 15, h = p >> 4;
  if (threadIdx.x < 16) sc[threadIdx.x] = scores[b * 256 + threadIdx.x * 16 + w];
  __syncthreads();
  float s = sb[0], b0 = sb[1];
  float mx = -1e30f;
#pragma unroll
  for (int hh = 0; hh < 16; ++hh) mx = fmaxf(mx, sc[hh]);
  float den = 0.f, my = 0.f;
#pragma unroll
  for (int hh = 0; hh < 16; ++hh) {
    float e = __expf(sc[hh] - mx);
    den += e;
    if (hh == h) my = e;
  }
  float coef = 1.0f + b0 + s * my / den;
  float xv = x[(size_t)(b * 512 + ch) * 256 + p];
  size_t o = (size_t)b * 165888 + (size_t)((h + 1) * 18 + (w + 1)) * 512 + ch;
  AM[o] = f2h(coef * xv);
  H0[o] = f2h(xv);
}

// ---------------------------------------------------------------------------
// Fused 4-gate 3x3 conv, implicit GEMM (fp16 MFMA 16x16x32, fp32 acc).
// Grid 256 = [b 8][chgrp 32], 512 thr (8 waves), N=256 full image. B back in
// LDS (R4's direct-global B was L1-throughput-bound: VGPR 52, MfmaUtil 15%).
// Two fixes this round:
//  1. B layout [row 18][slot 4][col 18][8ch]: granule%8 = (2*slot+col)%8, so
//     every 8-lane group of ds_read_b128 spans all 8 bank-slots -> conflict-
//     free (R3's col-major slots gave exactly 8 extra cyc/read = 4.7M).
//     DMA stays LDS-linear; the per-lane GLOBAL source supplies the layout
//     (padded images make every source address valid -> no masking).
//  2. T4 counted-vmcnt pipeline: uniform 8 DMAs/wave/stage (5 A + 3 B, tail
//     clamped), then "s_waitcnt vmcnt(8)" + raw s_barrier -> next chunk's
//     loads stay in flight across the barrier (syncthreads was draining
//     vmcnt(0) every chunk = R1/R2/R3's hidden serialization). Second raw
//     barrier (no drain) protects the double-buffer WAR.
// Wave (mw=wave>>2, nw=wave&3) owns gates {2mw,2mw+1} x image rows
// {4nw..4nw+3} -> acc[2][4]; 36 LDS reads feed 72 MFMAs per chunk.
// MODE 0: chunks 0-15 = W on AM (G=acc+biases at k==15), 16-31 = U on H0;
//         LSTM c_src=x.  MODE 1: z=acc+G; LSTM; c,h out.  MODE 2: d_out.
// ---------------------------------------------------------------------------
template <int MODE>
__launch_bounds__(512, 2)
__global__ void conv4(const u16* __restrict__ inA, const u16* __restrict__ inH,
                      const u16* __restrict__ wW, const u16* __restrict__ wU,
                      const float* __restrict__ bWi, const float* __restrict__ bUi,
                      const float* __restrict__ bWf, const float* __restrict__ bUf,
                      const float* __restrict__ bWo, const float* __restrict__ bUo,
                      const float* __restrict__ bWc, const float* __restrict__ bUc,
                      float* __restrict__ G, const float* __restrict__ c_src,
                      float* __restrict__ c_dst, u16* __restrict__ h_out,
                      float* __restrict__ out) {
  __shared__ __align__(16) u16 Alds[2][20480];  // 40 granule-rows (36 real + 4 pad)
  __shared__ __align__(16) u16 Blds[2][12288];  // 24 granule-rows (20.25 real)
  const int tid = threadIdx.x;
  const int chgrp = blockIdx.x & 31;
  const int b = blockIdx.x >> 5;
  const int wave = tid >> 6, lane = tid & 63;
  const int row = lane & 15, quad = lane >> 4;
  const int nw = wave & 3, mw = wave >> 2;
  const int NCH = (MODE == 0) ? 32 : 16;

  const u16* wsrcW = wW + (size_t)chgrp * 294912;
  const u16* wsrcU = wU + (size_t)chgrp * 294912;
  const u16* imgA = inA + (size_t)b * 165888;   // padded [18][18][512]
  const u16* imgH = inH + (size_t)b * 165888;

  // Per-lane global source offsets for the B staging DMA (loop-invariant):
  // LDS granule g = (row*4 + slot)*18 + col  <-  img[(row*18+col)*512 + slot*8]
  int boff[3];
#pragma unroll
  for (int j = 0; j < 3; ++j) {
    int g = (wave * 3 + j) * 64 + lane;
    g = g < 1296 ? g : 1295;                   // clamp tail (dup, never read)
    int r = g / 72, rem = g - r * 72;
    int s = rem / 18, col = rem - s * 18;
    boff[j] = (r * 18 + col) * 512 + s * 8;
  }

  auto stage = [&](int k, int bb) {
    const u16* gw;
    const u16* gi;
    if (MODE == 0 && k < 16) { gw = wsrcW + k * 18432; gi = imgA; }
    else                     { gw = wsrcU + (k & 15) * 18432; gi = imgH; }
    const int kc = (k & 15) * 32;
#pragma unroll
    for (int i = 0; i < 5; ++i) {              // 5 A-DMAs/wave (idx>=36 dup)
      int idx = wave * 5 + i;
      int sidx = idx < 36 ? idx : 35;
      gl16(gw + (sidx * 64 + lane) * 8, &Alds[bb][idx * 512]);
    }
#pragma unroll
    for (int j = 0; j < 3; ++j)                // 3 B-DMAs/wave
      gl16(gi + kc + boff[j], &Blds[bb][(wave * 3 + j) * 512]);
  };

  f32x4 acc[2][4];  // [m gate][jj image row]
#pragma unroll
  for (int m = 0; m < 2; ++m)
#pragma unroll
    for (int jj = 0; jj < 4; ++jj) acc[m][jj] = (f32x4){0.f, 0.f, 0.f, 0.f};

  const int ch0 = chgrp * 16 + quad * 4;
  float* gptr = G + (size_t)blockIdx.x * 16384 + wave * 2048 + lane * 4;

  stage(0, 0);
  asm volatile("s_waitcnt vmcnt(0)" ::: "memory");
  __builtin_amdgcn_sched_barrier(0);
  __builtin_amdgcn_s_barrier();
  __builtin_amdgcn_sched_barrier(0);

#pragma unroll 1
  for (int k = 0; k < NCH; ++k) {
    const int cur = k & 1;
    if (k + 1 < NCH) {
      stage(k + 1, cur ^ 1);                   // issue next-chunk DMAs (8/wave)
      asm volatile("s_waitcnt vmcnt(8)" ::: "memory");  // chunk-k landed; k+1 in flight
    } else {
      asm volatile("s_waitcnt vmcnt(0)" ::: "memory");
    }
    __builtin_amdgcn_sched_barrier(0);
    __builtin_amdgcn_s_barrier();              // all waves' chunk-k data visible
    __builtin_amdgcn_sched_barrier(0);
    const u16* Ab = &Alds[cur][0];
    const u16* Bb = &Blds[cur][0];
#pragma unroll
    for (int kx = 0; kx < 3; ++kx) {
      f16x8 bfr[6];                            // padded rows 4nw .. 4nw+5
#pragma unroll
      for (int rr = 0; rr < 6; ++rr)
        bfr[rr] = *(const f16x8*)(&Bb[(((4 * nw + rr) * 4 + quad) * 18 + row + kx) * 8]);
      f16x8 afr[6];                            // (ky 0..2) x (m 0..1)
#pragma unroll
      for (int ky = 0; ky < 3; ++ky)
#pragma unroll
        for (int m = 0; m < 2; ++m)
          afr[ky * 2 + m] = *(const f16x8*)(&Ab[((ky * 3 + kx) * 4 + 2 * mw + m) * 512 + lane * 8]);
#pragma unroll
      for (int ky = 0; ky < 3; ++ky)
#pragma unroll
        for (int m = 0; m < 2; ++m)
#pragma unroll
          for (int jj = 0; jj < 4; ++jj)
            acc[m][jj] = __builtin_amdgcn_mfma_f32_16x16x32_f16(afr[ky * 2 + m], bfr[jj + ky],
                                                                acc[m][jj], 0, 0, 0);
    }
    if constexpr (MODE == 0) {
      if (k == 15) {  // W-half done: add biases, persist G = conv(AM,W)+bW+bU
#pragma unroll
        for (int m = 0; m < 2; ++m) {
          int g = 2 * mw + m;
          const float* bw = g == 0 ? bWi : g == 1 ? bWf : g == 2 ? bWo : bWc;
          const float* bu = g == 0 ? bUi : g == 1 ? bUf : g == 2 ? bUo : bUc;
          f32x4 bias;
#pragma unroll
          for (int r = 0; r < 4; ++r) bias[r] = bw[ch0 + r] + bu[ch0 + r];
#pragma unroll
          for (int jj = 0; jj < 4; ++jj) {
            acc[m][jj] = acc[m][jj] + bias;
            *(f32x4*)(gptr + (m * 4 + jj) * 256) = acc[m][jj];
          }
        }
      }
    }
    __builtin_amdgcn_sched_barrier(0);
    __builtin_amdgcn_s_barrier();              // done reading cur before k+2's stage overwrites it
    __builtin_amdgcn_sched_barrier(0);
  }

  // ---- epilogue: reunite gates (mw=1 -> mw=0 via LDS), LSTM update ----
  if constexpr (MODE != 0) {
#pragma unroll
    for (int m = 0; m < 2; ++m)
#pragma unroll
      for (int jj = 0; jj < 4; ++jj)
        acc[m][jj] = acc[m][jj] + *(const f32x4*)(gptr + (m * 4 + jj) * 256);
  }
  float* X = (float*)&Alds[0][0];  // 32 KB exchange buffer (Alds[0] is dead: last cur==1)
  if (mw == 1) {
#pragma unroll
    for (int m = 0; m < 2; ++m)
#pragma unroll
      for (int jj = 0; jj < 4; ++jj)
        *(f32x4*)(X + (size_t)(((nw * 2 + m) * 4 + jj) * 256) + lane * 4) = acc[m][jj];
  }
  __syncthreads();
  if (mw == 0) {
#pragma unroll
    for (int jj = 0; jj < 4; ++jj) {
      const int p = (4 * nw + jj) * 16 + row;
      f32x4 zi = acc[0][jj], zf = acc[1][jj];
      f32x4 zo = *(const f32x4*)(X + (size_t)(((nw * 2 + 0) * 4 + jj) * 256) + lane * 4);
      f32x4 zg = *(const f32x4*)(X + (size_t)(((nw * 2 + 1) * 4 + jj) * 256) + lane * 4);
      f32x4 cold;
#pragma unroll
      for (int r = 0; r < 4; ++r)
        cold[r] = c_src[(size_t)(b * 512 + ch0 + r) * 256 + p];
      f32x4 cnew, hv;
#pragma unroll
      for (int r = 0; r < 4; ++r) {
        float iv = sigm(zi[r]);
        float fv = sigm(zf[r]);
        float ov = sigm(zo[r]);
        float gv = tanh_(zg[r]);
        float cn = fmaf(gv, iv, fv * cold[r]);
        cnew[r] = cn;
        hv[r] = tanh_(cn) * ov;
      }
      if constexpr (MODE != 2) {
#pragma unroll
        for (int r = 0; r < 4; ++r)
          c_dst[(size_t)(b * 512 + ch0 + r) * 256 + p] = cnew[r];
        us4 hb;
        hb[0] = f2h(hv[0]); hb[1] = f2h(hv[1]);
        hb[2] = f2h(hv[2]); hb[3] = f2h(hv[3]);
        *(us4*)(h_out + (size_t)b * 165888 + (size_t)((4 * nw + jj + 1) * 18 + row + 1) * 512 + ch0) = hb;
      } else {
#pragma unroll
        for (int r = 0; r < 4; ++r)
          out[(size_t)(b * 512 + ch0 + r) * 256 + p] = hv[r];
      }
    }
  }
}

extern "C" void kernel_launch(void* const* d_in, const int* in_sizes, int n_in,
                              void* d_out, int out_size, void* d_ws, size_t ws_size,
                              hipStream_t stream) {
  const float* x    = (const float*)d_in[0];
  const float* txt  = (const float*)d_in[1];
  const float* Wi_w = (const float*)d_in[7];
  const float* Wi_b = (const float*)d_in[8];
  const float* Ui_w = (const float*)d_in[9];
  const float* Ui_b = (const float*)d_in[10];
  const float* Wf_w = (const float*)d_in[11];
  const float* Wf_b = (const float*)d_in[12];
  const float* Uf_w = (const float*)d_in[13];
  const float* Uf_b = (const float*)d_in[14];
  const float* Wc_w = (const float*)d_in[15];
  const float* Wc_b = (const float*)d_in[16];
  const float* Uc_w = (const float*)d_in[17];
  const float* Uc_b = (const float*)d_in[18];
  const float* Wo_w = (const float*)d_in[19];
  const float* Wo_b = (const float*)d_in[20];
  const float* Uo_w = (const float*)d_in[21];
  const float* Uo_b = (const float*)d_in[22];
  const float* WQ   = (const float*)d_in[23];
  const float* WK   = (const float*)d_in[24];
  const float* WV   = (const float*)d_in[25];
  const float* Wsw  = (const float*)d_in[26];
  const float* Wsb  = (const float*)d_in[27];
  (void)in_sizes; (void)n_in; (void)ws_size;

  char* ws = (char*)d_ws;
  size_t off = 0;
  auto carve = [&](size_t n) {
    char* p = ws + off;
    off += (n + 255) & ~(size_t)255;
    return p;
  };
  u16* WswzW    = (u16*)carve(18874368);   // 4x512x512x9 fp16, fragment-major
  u16* WswzU    = (u16*)carve(18874368);
  u16* AM       = (u16*)carve(2654208);    // fp16 padded [8][18][18][512]
  u16* H0       = (u16*)carve(2654208);
  u16* H1       = (u16*)carve(2654208);
  float* G      = (float*)carve(16777216); // fragment-layout W-conv + biases
  float* C      = (float*)carve(4194304);  // cell state, NCHW f32
  float* scores = (float*)carve(8192);     // [8 b][256 p]
  float* sb     = (float*)carve(256);      // s, b0

  hipMemsetAsync(scores, 0, 8192, stream);   // scores accumulated via atomicAdd
  hipMemsetAsync(AM, 0, 2654208, stream);    // zero borders of padded images
  hipMemsetAsync(H0, 0, 2654208, stream);
  hipMemsetAsync(H1, 0, 2654208, stream);

  prep_scores<<<2048, 256, 0, stream>>>(WQ, WK, txt, WV, Wsw, Wsb, scores, sb);
  prep_swz<<<1024, 512, 0, stream>>>(Wi_w, Wf_w, Wo_w, Wc_w,
                                     Ui_w, Uf_w, Uo_w, Uc_w, WswzW, WswzU);
  prep_inputs<<<4096, 256, 0, stream>>>(x, scores, sb, AM, H0);

  // t=0 fused (W on AM + U on H0), then 3 more timesteps ping-ponging h.
  conv4<0><<<256, 512, 0, stream>>>(AM, H0, WswzW, WswzU,
                                    Wi_b, Ui_b, Wf_b, Uf_b, Wo_b, Uo_b, Wc_b, Uc_b,
                                    G, x, C, H1, nullptr);
  conv4<1><<<256, 512, 0, stream>>>(nullptr, H1, nullptr, WswzU,
                                    nullptr, nullptr, nullptr, nullptr,
                                    nullptr, nullptr, nullptr, nullptr,
                                    G, C, C, H0, nullptr);
  conv4<1><<<256, 512, 0, stream>>>(nullptr, H0, nullptr, WswzU,
                                    nullptr, nullptr, nullptr, nullptr,
                                    nullptr, nullptr, nullptr, nullptr,
                                    G, C, C, H1, nullptr);
  conv4<2><<<256, 512, 0, stream>>>(nullptr, H1, nullptr, WswzU,
                                    nullptr, nullptr, nullptr, nullptr,
                                    nullptr, nullptr, nullptr, nullptr,
                                    G, C, nullptr, nullptr, (float*)d_out);
}